// Round 1
// baseline (1045.840 us; speedup 1.0000x reference)
//
#include <hip/hip_runtime.h>
#include <hip/hip_bf16.h>
#include <math.h>

typedef __attribute__((ext_vector_type(4))) float  f32x4;
typedef __attribute__((ext_vector_type(8))) __bf16 bf16x8;
typedef __attribute__((ext_vector_type(4))) __bf16 bf16x4;

#define NBATCH 512
#define NFEAT  2048
#define NCENT  1000
#define NCENTP 1024
#define NCLS   50030

// ---------------- small helpers ----------------
__device__ __forceinline__ f32x4 fzero4() {
  f32x4 o; o[0] = 0.f; o[1] = 0.f; o[2] = 0.f; o[3] = 0.f; return o;
}
__device__ __forceinline__ bf16x8 bzero8() {
  bf16x8 o;
#pragma unroll
  for (int i = 0; i < 8; ++i) o[i] = (__bf16)0.f;
  return o;
}
__device__ __forceinline__ bf16x8 cvt8(f32x4 a, f32x4 b) {
  bf16x8 o;
  o[0] = (__bf16)a[0]; o[1] = (__bf16)a[1]; o[2] = (__bf16)a[2]; o[3] = (__bf16)a[3];
  o[4] = (__bf16)b[0]; o[5] = (__bf16)b[1]; o[6] = (__bf16)b[2]; o[7] = (__bf16)b[3];
  return o;
}

// ---------------- GEMM core ----------------
// C[128x128] tile of A[M,K] @ B^T where B is [N,K] row-major ("BT" layout).
// 256 threads = 4 waves in 2x2 arrangement; each wave owns 64x64 via 4x4
// mfma_f32_16x16x32_bf16. LDS is fragment-ordered: element (row r, k-col
// g*8+e) of the staged 128x32 tile lives at ((r>>4)*4 + g)*16 + (r&15))*8 + e,
// so both ds_write_b128 (staging) and ds_read_b128 (fragments) are linear
// 16B/lane -> conflict-free. A-frag row = lane&15, k-group = lane>>4 for BOTH
// operands => result correct for any hardware k-permutation.
// Staging is T14-split: global loads issued before MFMA, LDS writes after.
template <bool ABF, bool BBF, bool BG>
__device__ __forceinline__ void gemm_core(
    const void* __restrict__ Ap, int ldA,
    const void* __restrict__ Bp, int ldB,
    int m0, int n0, int K, int Brows,
    __bf16* lA, __bf16* lB, f32x4 (&acc)[4][4])
{
  const int tid  = threadIdx.x;
  const int r    = (tid >> 2) & 63;  // staging row within 64-row half
  const int c    = tid & 3;          // staging k-group (8 elems)
  const int lane = tid & 63;
  const int w    = tid >> 6;
  const int wr   = w >> 1, wc = w & 1;
  const int lr   = lane & 15, lg = lane >> 4;

  f32x4  Af[2][2], Bf[2][2];
  bf16x8 Ab[2], Bb[2];

  const int nk = K >> 5;  // BK = 32

  auto LD = [&](int ks) {
    const int k0 = ks << 5;
#pragma unroll
    for (int it = 0; it < 2; ++it) {
      const int ra = r + (it << 6);           // 0..127
      if constexpr (ABF) {
        const __bf16* A = (const __bf16*)Ap;
        Ab[it] = *(const bf16x8*)(A + (size_t)(m0 + ra) * ldA + k0 + c * 8);
      } else {
        const float* A = (const float*)Ap;
        const float* p = A + (size_t)(m0 + ra) * ldA + k0 + c * 8;
        Af[it][0] = *(const f32x4*)p;
        Af[it][1] = *(const f32x4*)(p + 4);
      }
      const bool ok = (!BG) || (n0 + ra < Brows);
      if constexpr (BBF) {
        const __bf16* Bm = (const __bf16*)Bp;
        if (ok) Bb[it] = *(const bf16x8*)(Bm + (size_t)(n0 + ra) * ldB + k0 + c * 8);
        else    Bb[it] = bzero8();
      } else {
        const float* Bm = (const float*)Bp;
        const float* p  = Bm + (size_t)(n0 + ra) * ldB + k0 + c * 8;
        if (ok) { Bf[it][0] = *(const f32x4*)p; Bf[it][1] = *(const f32x4*)(p + 4); }
        else    { Bf[it][0] = fzero4();         Bf[it][1] = fzero4(); }
      }
    }
  };

  auto ST = [&](int buf) {
    __bf16* la = lA + buf * 4096;
    __bf16* lb = lB + buf * 4096;
#pragma unroll
    for (int it = 0; it < 2; ++it) {
      const int ra  = r + (it << 6);
      const int off = ((((ra >> 4) << 2) + c) * 16 + (ra & 15)) * 8;
      if constexpr (ABF) *(bf16x8*)(la + off) = Ab[it];
      else               *(bf16x8*)(la + off) = cvt8(Af[it][0], Af[it][1]);
      if constexpr (BBF) *(bf16x8*)(lb + off) = Bb[it];
      else               *(bf16x8*)(lb + off) = cvt8(Bf[it][0], Bf[it][1]);
    }
  };

#pragma unroll
  for (int mi = 0; mi < 4; ++mi)
#pragma unroll
    for (int ni = 0; ni < 4; ++ni) acc[mi][ni] = fzero4();

  LD(0);
  ST(0);
  int cur = 0;
  for (int ks = 0; ks < nk; ++ks) {
    __syncthreads();                       // buf[cur] staged by all waves
    const bool more = (ks + 1 < nk);
    if (more) LD(ks + 1);                  // issue next-tile global loads early

    bf16x8 af[4], bfr[4];
#pragma unroll
    for (int mi = 0; mi < 4; ++mi) {
      const int t = wr * 4 + mi;
      af[mi] = *(const bf16x8*)(lA + cur * 4096 + ((t * 4 + lg) * 16 + lr) * 8);
    }
#pragma unroll
    for (int ni = 0; ni < 4; ++ni) {
      const int t = wc * 4 + ni;
      bfr[ni] = *(const bf16x8*)(lB + cur * 4096 + ((t * 4 + lg) * 16 + lr) * 8);
    }
#pragma unroll
    for (int mi = 0; mi < 4; ++mi)
#pragma unroll
      for (int ni = 0; ni < 4; ++ni)
        acc[mi][ni] = __builtin_amdgcn_mfma_f32_16x16x32_bf16(
            af[mi], bfr[ni], acc[mi][ni], 0, 0, 0);

    if (more) ST(cur ^ 1);                 // vmcnt-wait + LDS write, post-MFMA
    cur ^= 1;
  }
}

// C/D layout (verified): row = (lane>>4)*4 + q, col = lane&15, per 16x16 tile.
#define EPILOGUE_COORDS()                                        \
  const int lane = threadIdx.x & 63, w_ = threadIdx.x >> 6;      \
  const int wr = w_ >> 1, wc = w_ & 1;                           \
  const int lr = lane & 15, lg = lane >> 4;

// ---------------- kernels ----------------

// c2[c] = sum_f centroids[c][f]^2
__global__ __launch_bounds__(256) void k_rownorm(const float* __restrict__ M,
                                                 float* __restrict__ out)
{
  const int row = blockIdx.x, tid = threadIdx.x;
  __shared__ float red[4];
  const f32x4* p = (const f32x4*)(M + (size_t)row * NFEAT);
  float s = 0.f;
  for (int j = tid; j < NFEAT / 4; j += 256) {
    f32x4 v = p[j];
    s += v[0] * v[0] + v[1] * v[1] + v[2] * v[2] + v[3] * v[3];
  }
  for (int o = 32; o > 0; o >>= 1) s += __shfl_down(s, o, 64);
  if ((tid & 63) == 0) red[tid >> 6] = s;
  __syncthreads();
  if (tid == 0) out[row] = red[0] + red[1] + red[2] + red[3];
}

// S = c2 - 2*x@cent^T (z=0) and H = x@W_hall^T + b_hall (z=1), padded to 1024 cols.
__global__ __launch_bounds__(256) void k_gemm_sh(
    const float* __restrict__ x, const float* __restrict__ cent,
    const float* __restrict__ Whall, const float* __restrict__ bhall,
    const float* __restrict__ c2, float* __restrict__ S, float* __restrict__ H)
{
  __shared__ __bf16 lA[2 * 4096];
  __shared__ __bf16 lB[2 * 4096];
  const int m0 = blockIdx.y * 128, n0 = blockIdx.x * 128;
  const float* Bm = (blockIdx.z == 0) ? cent : Whall;
  f32x4 acc[4][4];
  gemm_core<false, false, true>(x, NFEAT, Bm, NFEAT, m0, n0, NFEAT, NCENT, lA, lB, acc);

  EPILOGUE_COORDS();
#pragma unroll
  for (int mi = 0; mi < 4; ++mi)
#pragma unroll
    for (int ni = 0; ni < 4; ++ni)
#pragma unroll
      for (int q = 0; q < 4; ++q) {
        const int row = m0 + wr * 64 + mi * 16 + lg * 4 + q;
        const int col = n0 + wc * 64 + ni * 16 + lr;
        const float v = acc[mi][ni][q];
        if (blockIdx.z == 0)
          S[(size_t)row * NCENTP + col] = (col < NCENT) ? (c2[col] - 2.f * v) : 1e30f;
        else
          H[(size_t)row * NCENTP + col] = (col < NCENT) ? (v + bhall[col]) : -1e30f;
      }
}

// per-row: x2, min-dist -> reach, softmax(H) -> P (bf16, padded cols = 0)
__global__ __launch_bounds__(256) void k_rowred(
    const float* __restrict__ x, const float* __restrict__ S,
    const float* __restrict__ H, __bf16* __restrict__ P,
    float* __restrict__ reach)
{
  const int b = blockIdx.x, tid = threadIdx.x;
  const int lane = tid & 63, w = tid >> 6;
  __shared__ float red[4];

  float s = 0.f;
  const f32x4* xp = (const f32x4*)(x + (size_t)b * NFEAT);
  for (int j = tid; j < NFEAT / 4; j += 256) {
    f32x4 v = xp[j];
    s += v[0] * v[0] + v[1] * v[1] + v[2] * v[2] + v[3] * v[3];
  }
  for (int o = 32; o > 0; o >>= 1) s += __shfl_down(s, o, 64);
  if (lane == 0) red[w] = s;
  __syncthreads();
  const float x2 = red[0] + red[1] + red[2] + red[3];
  __syncthreads();

  float mn = 1e30f;
  const float* Sr = S + (size_t)b * NCENTP;
  for (int j = tid; j < NCENTP; j += 256) mn = fminf(mn, Sr[j]);
  for (int o = 32; o > 0; o >>= 1) mn = fminf(mn, __shfl_down(mn, o, 64));
  if (lane == 0) red[w] = mn;
  __syncthreads();
  mn = fminf(fminf(red[0], red[1]), fminf(red[2], red[3]));
  __syncthreads();
  if (tid == 0) {
    const float d = sqrtf(fmaxf(x2 + mn, 0.f));
    reach[b] = 10.f / d;
  }

  const float* Hr = H + (size_t)b * NCENTP;
  float mx = -1e30f;
  for (int j = tid; j < NCENTP; j += 256) mx = fmaxf(mx, Hr[j]);
  for (int o = 32; o > 0; o >>= 1) mx = fmaxf(mx, __shfl_down(mx, o, 64));
  if (lane == 0) red[w] = mx;
  __syncthreads();
  mx = fmaxf(fmaxf(red[0], red[1]), fmaxf(red[2], red[3]));
  __syncthreads();

  float se = 0.f;
  for (int j = tid; j < NCENTP; j += 256) se += expf(Hr[j] - mx);
  for (int o = 32; o > 0; o >>= 1) se += __shfl_down(se, o, 64);
  if (lane == 0) red[w] = se;
  __syncthreads();
  const float inv = 1.f / (red[0] + red[1] + red[2] + red[3]);

  for (int j = tid; j < NCENTP; j += 256)
    P[(size_t)b * NCENTP + j] = (__bf16)(expf(Hr[j] - mx) * inv);
}

// centT[f][c] = bf16(centroids[c][f]); c in [0,1024) padded with 0
__global__ __launch_bounds__(256) void k_tcent(const float* __restrict__ cent,
                                               __bf16* __restrict__ centT)
{
  __shared__ float t[64][65];
  const int c0 = blockIdx.x * 64, f0 = blockIdx.y * 64;
  const int tid = threadIdx.x;
  const int i = tid >> 4, j4 = (tid & 15) * 4;
#pragma unroll
  for (int it = 0; it < 4; ++it) {
    const int ci = i + it * 16;
    f32x4 v;
    if (c0 + ci < NCENT) v = *(const f32x4*)(cent + (size_t)(c0 + ci) * NFEAT + f0 + j4);
    else                 v = fzero4();
    t[ci][j4] = v[0]; t[ci][j4 + 1] = v[1]; t[ci][j4 + 2] = v[2]; t[ci][j4 + 3] = v[3];
  }
  __syncthreads();
#pragma unroll
  for (int it = 0; it < 4; ++it) {
    const int fi = i + it * 16;
    bf16x4 o;
#pragma unroll
    for (int q = 0; q < 4; ++q) o[q] = (__bf16)t[j4 + q][fi];
    *(bf16x4*)(centT + (size_t)(f0 + fi) * NCENTP + c0 + j4) = o;
  }
}

// memfeat = P @ centroids   (as P[512,1024]bf16 @ centT[2048,1024]bf16 ^T)
__global__ __launch_bounds__(256) void k_gemm_mem(
    const __bf16* __restrict__ P, const __bf16* __restrict__ centT,
    float* __restrict__ memf)
{
  __shared__ __bf16 lA[2 * 4096];
  __shared__ __bf16 lB[2 * 4096];
  const int m0 = blockIdx.y * 128, n0 = blockIdx.x * 128;
  f32x4 acc[4][4];
  gemm_core<true, true, false>(P, NCENTP, centT, NCENTP, m0, n0, NCENTP, NFEAT, lA, lB, acc);

  EPILOGUE_COORDS();
#pragma unroll
  for (int mi = 0; mi < 4; ++mi)
#pragma unroll
    for (int ni = 0; ni < 4; ++ni)
#pragma unroll
      for (int q = 0; q < 4; ++q) {
        const int row = m0 + wr * 64 + mi * 16 + lg * 4 + q;
        const int col = n0 + wc * 64 + ni * 16 + lr;
        memf[(size_t)row * NFEAT + col] = acc[mi][ni][q];
      }
}

// sel = x@W_sel^T + b_sel; infused = tanh(sel)*memfeat (-> d_out section 3);
// fusedb = bf16(reach * (x + infused)) (-> phase E input)
__global__ __launch_bounds__(256) void k_gemm_sel(
    const float* __restrict__ x, const float* __restrict__ Wsel,
    const float* __restrict__ bsel, const float* __restrict__ memf,
    const float* __restrict__ reach, float* __restrict__ out_inf,
    __bf16* __restrict__ fusedb)
{
  __shared__ __bf16 lA[2 * 4096];
  __shared__ __bf16 lB[2 * 4096];
  const int m0 = blockIdx.y * 128, n0 = blockIdx.x * 128;
  f32x4 acc[4][4];
  gemm_core<false, false, false>(x, NFEAT, Wsel, NFEAT, m0, n0, NFEAT, NFEAT, lA, lB, acc);

  EPILOGUE_COORDS();
#pragma unroll
  for (int mi = 0; mi < 4; ++mi)
#pragma unroll
    for (int ni = 0; ni < 4; ++ni)
#pragma unroll
      for (int q = 0; q < 4; ++q) {
        const int row = m0 + wr * 64 + mi * 16 + lg * 4 + q;
        const int col = n0 + wc * 64 + ni * 16 + lr;
        const float tv  = tanhf(acc[mi][ni][q] + bsel[col]);
        const float inf = tv * memf[(size_t)row * NFEAT + col];
        out_inf[(size_t)row * NFEAT + col] = inf;
        fusedb[(size_t)row * NFEAT + col] =
            (__bf16)(reach[row] * (x[(size_t)row * NFEAT + col] + inf));
      }
}

// logits = fused @ W_cls^T + b_cls
__global__ __launch_bounds__(256) void k_gemm_cls(
    const __bf16* __restrict__ fusedb, const float* __restrict__ Wcls,
    const float* __restrict__ bcls, float* __restrict__ out)
{
  __shared__ __bf16 lA[2 * 4096];
  __shared__ __bf16 lB[2 * 4096];
  const int bx = blockIdx.x;
  const int m0 = (bx & 3) * 128;       // M-tile inner -> 4 consecutive blocks
  const int n0 = (bx >> 2) * 128;      // share the same W_cls panel via L2
  f32x4 acc[4][4];
  gemm_core<true, false, true>(fusedb, NFEAT, Wcls, NFEAT, m0, n0, NFEAT, NCLS, lA, lB, acc);

  EPILOGUE_COORDS();
#pragma unroll
  for (int mi = 0; mi < 4; ++mi)
#pragma unroll
    for (int ni = 0; ni < 4; ++ni)
#pragma unroll
      for (int q = 0; q < 4; ++q) {
        const int row = m0 + wr * 64 + mi * 16 + lg * 4 + q;
        const int col = n0 + wc * 64 + ni * 16 + lr;
        if (col < NCLS)
          out[(size_t)row * NCLS + col] = acc[mi][ni][q] + bcls[col];
      }
}

// ---------------- launch ----------------
extern "C" void kernel_launch(void* const* d_in, const int* in_sizes, int n_in,
                              void* d_out, int out_size, void* d_ws, size_t ws_size,
                              hipStream_t stream)
{
  (void)in_sizes; (void)n_in; (void)out_size; (void)ws_size;

  const float* x     = (const float*)d_in[0];
  const float* cent  = (const float*)d_in[1];
  const float* Whall = (const float*)d_in[2];
  const float* bhall = (const float*)d_in[3];
  const float* Wsel  = (const float*)d_in[4];
  const float* bsel  = (const float*)d_in[5];
  const float* Wcls  = (const float*)d_in[6];
  const float* bcls  = (const float*)d_in[7];
  float* out = (float*)d_out;

  char* ws = (char*)d_ws;
  float*  S      = (float*) (ws);                                   // 2 MiB
  float*  H      = (float*) (ws + (2u << 20));                      // 2 MiB
  float*  c2     = (float*) (ws + (4u << 20));                      // 16 KiB slot
  float*  reach  = (float*) (ws + (4u << 20) + (16u << 10));        // 16 KiB slot
  float*  memf   = (float*) (ws + (4u << 20) + (32u << 10));        // 4 MiB
  __bf16* P      = (__bf16*)(ws + (8u << 20) + (32u << 10));        // 1 MiB
  __bf16* centT  = (__bf16*)(ws + (9u << 20) + (32u << 10));        // 4 MiB
  __bf16* fusedb = (__bf16*)(ws + (13u << 20) + (32u << 10));       // 2 MiB
  // total ws use: ~15.03 MiB

  float* out_logits = out;
  float* out_x      = out + (size_t)NBATCH * NCLS;
  float* out_inf    = out_x + (size_t)NBATCH * NFEAT;

  k_rownorm<<<NCENT, 256, 0, stream>>>(cent, c2);
  k_gemm_sh<<<dim3(NCENTP / 128, NBATCH / 128, 2), 256, 0, stream>>>(
      x, cent, Whall, bhall, c2, S, H);
  k_tcent<<<dim3(NCENTP / 64, NFEAT / 64), 256, 0, stream>>>(cent, centT);
  k_rowred<<<NBATCH, 256, 0, stream>>>(x, S, H, P, reach);
  k_gemm_mem<<<dim3(NFEAT / 128, NBATCH / 128), 256, 0, stream>>>(P, centT, memf);
  k_gemm_sel<<<dim3(NFEAT / 128, NBATCH / 128), 256, 0, stream>>>(
      x, Wsel, bsel, memf, reach, out_inf, fusedb);
  hipMemcpyAsync(out_x, x, (size_t)NBATCH * NFEAT * sizeof(float),
                 hipMemcpyDeviceToDevice, stream);
  k_gemm_cls<<<((NCLS + 127) / 128) * 4, 256, 0, stream>>>(
      fusedb, Wcls, bcls, out_logits);
}

// Round 4
// 814.240 us; speedup vs baseline: 1.2844x; 1.2844x over previous
//
#include <hip/hip_runtime.h>
#include <hip/hip_bf16.h>
#include <math.h>

typedef __attribute__((ext_vector_type(4))) float  f32x4;
typedef __attribute__((ext_vector_type(8))) __bf16 bf16x8;
typedef __attribute__((ext_vector_type(4))) __bf16 bf16x4;

#define NBATCH 512
#define NFEAT  2048
#define NCENT  1000
#define NCENTP 1024
#define NCLS   50030

// ---------------- small helpers ----------------
__device__ __forceinline__ f32x4 fzero4() {
  f32x4 o; o[0] = 0.f; o[1] = 0.f; o[2] = 0.f; o[3] = 0.f; return o;
}
__device__ __forceinline__ bf16x8 bzero8() {
  bf16x8 o;
#pragma unroll
  for (int i = 0; i < 8; ++i) o[i] = (__bf16)0.f;
  return o;
}
__device__ __forceinline__ bf16x8 cvt8(f32x4 a, f32x4 b) {
  bf16x8 o;
  o[0] = (__bf16)a[0]; o[1] = (__bf16)a[1]; o[2] = (__bf16)a[2]; o[3] = (__bf16)a[3];
  o[4] = (__bf16)b[0]; o[5] = (__bf16)b[1]; o[6] = (__bf16)b[2]; o[7] = (__bf16)b[3];
  return o;
}

// ---------------- GEMM core ----------------
// BM x 128 tile of A[M,K] @ B^T (B is [N,K] row-major). 256 thr = 4 waves 2x2;
// wave owns (BM/2)x64 via (BM/32)x4 mfma_f32_16x16x32_bf16.
//
// LDS layout, 16B-slot granularity, XOR bank swizzle:
//   slot(row,g) = (row>>4)*64 + g*16 + ((row&15) ^ (g<<1))
// Write side (lane 8t..8t+7 = rows {2t,2t+1} x g 0..3): slot%8 spans
// {2t^0,2t^2,2t^4,2t^6} + odd -> 8 distinct bank-quads, conflict-free.
// Read side (b128 frag: row=t*16+lr, g=lg): each 8-lane beat has distinct
// (lr^(lg<<1))%8 -> conflict-free. (Round-1 layout 8-way-conflicted on writes:
// SQ_LDS_BANK_CONFLICT 3.8e7 = ~17% of cls cycles.)
//
// Pipeline: 3-buffer LDS ring, prefetch distance 2:
//   iter k: ST(regs->buf[(k+1)%3]); LD(tile k+2 -> regs); MFMA(buf[k%3]); bar
// -> each global load gets ~1 full iteration + barrier of latency cover.
// Ring-safety: buf[(k+1)%3] was last read at iter k-2, two barriers ago.
template <int BM, bool ABF, bool BBF, bool BG>
__device__ __forceinline__ void gemm_core(
    const void* __restrict__ Ap, int ldA,
    const void* __restrict__ Bp, int ldB,
    int m0, int n0, int K, int Brows,
    __bf16* lA, __bf16* lB, f32x4 (&acc)[BM / 32][4])
{
  constexpr int MI    = BM / 32;   // A 16-tiles per wave
  constexpr int ITA   = BM / 64;   // A staging iterations per thread
  constexpr int ATILE = BM * 32;   // A tile elems
  constexpr int BTILE = 4096;      // B tile elems (128x32)

  const int tid  = threadIdx.x;
  const int r    = (tid >> 2) & 63;
  const int g    = tid & 3;
  const int lane = tid & 63;
  const int w    = tid >> 6;
  const int wr   = w >> 1, wc = w & 1;
  const int lr   = lane & 15, lg = lane >> 4;

  f32x4  Af[2][2], Bf[2][2];
  bf16x8 Ab[2], Bb[2];

  const int nk = K >> 5;  // BK = 32

  auto LD = [&](int ks) {
    const int k0 = ks << 5;
#pragma unroll
    for (int it = 0; it < ITA; ++it) {
      const int ra = r + (it << 6);
      if constexpr (ABF) {
        const __bf16* A = (const __bf16*)Ap;
        Ab[it] = *(const bf16x8*)(A + (size_t)(m0 + ra) * ldA + k0 + g * 8);
      } else {
        const float* A = (const float*)Ap;
        const float* p = A + (size_t)(m0 + ra) * ldA + k0 + g * 8;
        Af[it][0] = *(const f32x4*)p;
        Af[it][1] = *(const f32x4*)(p + 4);
      }
    }
#pragma unroll
    for (int it = 0; it < 2; ++it) {
      const int rb = r + (it << 6);
      const bool ok = (!BG) || (n0 + rb < Brows);
      if constexpr (BBF) {
        const __bf16* Bm = (const __bf16*)Bp;
        if (ok) Bb[it] = *(const bf16x8*)(Bm + (size_t)(n0 + rb) * ldB + k0 + g * 8);
        else    Bb[it] = bzero8();
      } else {
        const float* Bm = (const float*)Bp;
        const float* p  = Bm + (size_t)(n0 + rb) * ldB + k0 + g * 8;
        if (ok) { Bf[it][0] = *(const f32x4*)p; Bf[it][1] = *(const f32x4*)(p + 4); }
        else    { Bf[it][0] = fzero4();         Bf[it][1] = fzero4(); }
      }
    }
  };

  auto ST = [&](int buf) {
    __bf16* la = lA + buf * ATILE;
    __bf16* lb = lB + buf * BTILE;
#pragma unroll
    for (int it = 0; it < ITA; ++it) {
      const int ra   = r + (it << 6);
      const int slot = ((ra >> 4) << 6) + (g << 4) + ((ra & 15) ^ (g << 1));
      if constexpr (ABF) *(bf16x8*)(la + slot * 8) = Ab[it];
      else               *(bf16x8*)(la + slot * 8) = cvt8(Af[it][0], Af[it][1]);
    }
#pragma unroll
    for (int it = 0; it < 2; ++it) {
      const int rb   = r + (it << 6);
      const int slot = ((rb >> 4) << 6) + (g << 4) + ((rb & 15) ^ (g << 1));
      if constexpr (BBF) *(bf16x8*)(lb + slot * 8) = Bb[it];
      else               *(bf16x8*)(lb + slot * 8) = cvt8(Bf[it][0], Bf[it][1]);
    }
  };

#pragma unroll
  for (int mi = 0; mi < MI; ++mi)
#pragma unroll
    for (int ni = 0; ni < 4; ++ni) acc[mi][ni] = fzero4();

  LD(0);
  ST(0);
  if (nk > 1) LD(1);
  __syncthreads();

  for (int ks = 0; ks < nk; ++ks) {
    if (ks + 1 < nk) ST((ks + 1) % 3);   // regs (tile ks+1) -> next ring buf
    if (ks + 2 < nk) LD(ks + 2);         // issue loads 2 tiles ahead

    const __bf16* la = lA + (ks % 3) * ATILE;
    const __bf16* lb = lB + (ks % 3) * BTILE;
    bf16x8 af[MI], bfr[4];
#pragma unroll
    for (int mi = 0; mi < MI; ++mi) {
      const int t = wr * MI + mi;
      af[mi] = *(const bf16x8*)(la + ((t << 6) + (lg << 4) + (lr ^ (lg << 1))) * 8);
    }
#pragma unroll
    for (int ni = 0; ni < 4; ++ni) {
      const int t = wc * 4 + ni;
      bfr[ni] = *(const bf16x8*)(lb + ((t << 6) + (lg << 4) + (lr ^ (lg << 1))) * 8);
    }
#pragma unroll
    for (int mi = 0; mi < MI; ++mi)
#pragma unroll
      for (int ni = 0; ni < 4; ++ni)
        acc[mi][ni] = __builtin_amdgcn_mfma_f32_16x16x32_bf16(
            af[mi], bfr[ni], acc[mi][ni], 0, 0, 0);

    __syncthreads();
  }
}

// C/D layout (verified): row = (lane>>4)*4 + q, col = lane&15, per 16x16 tile.
#define EPILOGUE_COORDS()                                        \
  const int lane = threadIdx.x & 63, w_ = threadIdx.x >> 6;      \
  const int wr = w_ >> 1, wc = w_ & 1;                           \
  const int lr = lane & 15, lg = lane >> 4;

// ---------------- kernels ----------------

// c2[c] = sum_f centroids[c][f]^2
__global__ __launch_bounds__(256) void k_rownorm(const float* __restrict__ M,
                                                 float* __restrict__ out)
{
  const int row = blockIdx.x, tid = threadIdx.x;
  __shared__ float red[4];
  const f32x4* p = (const f32x4*)(M + (size_t)row * NFEAT);
  float s = 0.f;
  for (int j = tid; j < NFEAT / 4; j += 256) {
    f32x4 v = p[j];
    s += v[0] * v[0] + v[1] * v[1] + v[2] * v[2] + v[3] * v[3];
  }
  for (int o = 32; o > 0; o >>= 1) s += __shfl_down(s, o, 64);
  if ((tid & 63) == 0) red[tid >> 6] = s;
  __syncthreads();
  if (tid == 0) out[row] = red[0] + red[1] + red[2] + red[3];
}

// centT[f][c] = bf16(centroids[c][f]); c padded to 1024 with 0
__global__ __launch_bounds__(256) void k_tcent(const float* __restrict__ cent,
                                               __bf16* __restrict__ centT)
{
  __shared__ float t[64][65];
  const int c0 = blockIdx.x * 64, f0 = blockIdx.y * 64;
  const int tid = threadIdx.x;
  const int i = tid >> 4, j4 = (tid & 15) * 4;
#pragma unroll
  for (int it = 0; it < 4; ++it) {
    const int ci = i + it * 16;
    f32x4 v;
    if (c0 + ci < NCENT) v = *(const f32x4*)(cent + (size_t)(c0 + ci) * NFEAT + f0 + j4);
    else                 v = fzero4();
    t[ci][j4] = v[0]; t[ci][j4 + 1] = v[1]; t[ci][j4 + 2] = v[2]; t[ci][j4 + 3] = v[3];
  }
  __syncthreads();
#pragma unroll
  for (int it = 0; it < 4; ++it) {
    const int fi = i + it * 16;
    bf16x4 o;
#pragma unroll
    for (int q = 0; q < 4; ++q) o[q] = (__bf16)t[j4 + q][fi];
    *(bf16x4*)(centT + (size_t)(f0 + fi) * NCENTP + c0 + j4) = o;
  }
}

// One fused GEMM: x @ [cent | W_hall | W_sel]^T -> S | H | tanh(sel+b)
// N = 1024 + 1024 + 2048 = 4096 (segments padded). BM=64 -> 256 blocks.
__global__ __launch_bounds__(256) void k_gemm_big(
    const float* __restrict__ x, const float* __restrict__ cent,
    const float* __restrict__ Whall, const float* __restrict__ bhall,
    const float* __restrict__ Wsel, const float* __restrict__ bsel,
    const float* __restrict__ c2, float* __restrict__ S,
    float* __restrict__ H, float* __restrict__ selt)
{
  __shared__ __bf16 lA[3 * 64 * 32];
  __shared__ __bf16 lB[3 * 4096];
  // XCD chunk swizzle: 256 blocks = 8 XCD x 32; m innermost so each XCD's
  // chunk covers 4 whole B-panels (panel fetched once per XCD L2).
  const int logical = ((blockIdx.x & 7) << 5) + (blockIdx.x >> 3);
  const int m0 = (logical & 7) * 64;
  const int n0 = (logical >> 3) * 128;

  const float* Bp; int brows, segn, seg;
  if (n0 < 1024)      { Bp = cent;  brows = NCENT; segn = n0;        seg = 0; }
  else if (n0 < 2048) { Bp = Whall; brows = NCENT; segn = n0 - 1024; seg = 1; }
  else                { Bp = Wsel;  brows = NFEAT; segn = n0 - 2048; seg = 2; }

  f32x4 acc[2][4];
  gemm_core<64, false, false, true>(x, NFEAT, Bp, NFEAT, m0, segn, NFEAT, brows,
                                    lA, lB, acc);

  EPILOGUE_COORDS();
#pragma unroll
  for (int mi = 0; mi < 2; ++mi)
#pragma unroll
    for (int ni = 0; ni < 4; ++ni)
#pragma unroll
      for (int q = 0; q < 4; ++q) {
        const int row = m0 + (wr * 2 + mi) * 16 + lg * 4 + q;
        const int cl  = segn + wc * 64 + ni * 16 + lr;   // segment-local col
        const float v = acc[mi][ni][q];
        if (seg == 0)
          S[(size_t)row * NCENTP + cl] = (cl < NCENT) ? (c2[cl] - 2.f * v) : 1e30f;
        else if (seg == 1)
          H[(size_t)row * NCENTP + cl] = (cl < NCENT) ? (v + bhall[cl]) : -1e30f;
        else
          selt[(size_t)row * NFEAT + cl] = tanhf(v + bsel[cl]);
      }
}

// per-row: x2, min-dist -> reach, softmax(H) -> P (bf16, padded cols -> 0)
__global__ __launch_bounds__(256) void k_rowred(
    const float* __restrict__ x, const float* __restrict__ S,
    const float* __restrict__ H, __bf16* __restrict__ P,
    float* __restrict__ reach)
{
  const int b = blockIdx.x, tid = threadIdx.x;
  const int lane = tid & 63, w = tid >> 6;
  __shared__ float red[4];

  float s = 0.f;
  const f32x4* xp = (const f32x4*)(x + (size_t)b * NFEAT);
  for (int j = tid; j < NFEAT / 4; j += 256) {
    f32x4 v = xp[j];
    s += v[0] * v[0] + v[1] * v[1] + v[2] * v[2] + v[3] * v[3];
  }
  for (int o = 32; o > 0; o >>= 1) s += __shfl_down(s, o, 64);
  if (lane == 0) red[w] = s;
  __syncthreads();
  const float x2 = red[0] + red[1] + red[2] + red[3];
  __syncthreads();

  float mn = 1e30f;
  const float* Sr = S + (size_t)b * NCENTP;
  for (int j = tid; j < NCENTP; j += 256) mn = fminf(mn, Sr[j]);
  for (int o = 32; o > 0; o >>= 1) mn = fminf(mn, __shfl_down(mn, o, 64));
  if (lane == 0) red[w] = mn;
  __syncthreads();
  mn = fminf(fminf(red[0], red[1]), fminf(red[2], red[3]));
  __syncthreads();
  if (tid == 0) {
    const float d = sqrtf(fmaxf(x2 + mn, 0.f));
    reach[b] = 10.f / d;
  }

  const float* Hr = H + (size_t)b * NCENTP;
  float mx = -1e30f;
  for (int j = tid; j < NCENTP; j += 256) mx = fmaxf(mx, Hr[j]);
  for (int o = 32; o > 0; o >>= 1) mx = fmaxf(mx, __shfl_down(mx, o, 64));
  if (lane == 0) red[w] = mx;
  __syncthreads();
  mx = fmaxf(fmaxf(red[0], red[1]), fmaxf(red[2], red[3]));
  __syncthreads();

  float se = 0.f;
  for (int j = tid; j < NCENTP; j += 256) se += expf(Hr[j] - mx);
  for (int o = 32; o > 0; o >>= 1) se += __shfl_down(se, o, 64);
  if (lane == 0) red[w] = se;
  __syncthreads();
  const float inv = 1.f / (red[0] + red[1] + red[2] + red[3]);

  for (int j = tid; j < NCENTP; j += 256)
    P[(size_t)b * NCENTP + j] = (__bf16)(expf(Hr[j] - mx) * inv);
}

// memfeat = P @ centroids  (P[512,1024]bf16 @ centT[2048,1024]bf16 ^T)
__global__ __launch_bounds__(256) void k_gemm_mem(
    const __bf16* __restrict__ P, const __bf16* __restrict__ centT,
    float* __restrict__ memf)
{
  __shared__ __bf16 lA[3 * 64 * 32];
  __shared__ __bf16 lB[3 * 4096];
  const int logical = ((blockIdx.x & 7) << 4) + (blockIdx.x >> 3);  // 128 blocks
  const int m0 = (logical & 7) * 64;
  const int n0 = (logical >> 3) * 128;
  f32x4 acc[2][4];
  gemm_core<64, true, true, false>(P, NCENTP, centT, NCENTP, m0, n0, NCENTP,
                                   NFEAT, lA, lB, acc);

  EPILOGUE_COORDS();
#pragma unroll
  for (int mi = 0; mi < 2; ++mi)
#pragma unroll
    for (int ni = 0; ni < 4; ++ni)
#pragma unroll
      for (int q = 0; q < 4; ++q) {
        const int row = m0 + (wr * 2 + mi) * 16 + lg * 4 + q;
        const int col = n0 + wc * 64 + ni * 16 + lr;
        memf[(size_t)row * NFEAT + col] = acc[mi][ni][q];
      }
}

// elementwise: infused = selt*memf; out_x = x; fusedb = bf16(reach*(x+infused))
__global__ __launch_bounds__(256) void k_fuse(
    const float* __restrict__ x, const float* __restrict__ selt,
    const float* __restrict__ memf, const float* __restrict__ reach,
    float* __restrict__ out_x, float* __restrict__ out_inf,
    __bf16* __restrict__ fusedb)
{
  const int i   = blockIdx.x * 256 + threadIdx.x;     // f32x4 index
  const int row = (i * 4) >> 11;                      // /NFEAT
  f32x4 xv = ((const f32x4*)x)[i];
  f32x4 sv = ((const f32x4*)selt)[i];
  f32x4 mv = ((const f32x4*)memf)[i];
  const float rc = reach[row];
  f32x4 inf;
  bf16x4 fb;
#pragma unroll
  for (int j = 0; j < 4; ++j) {
    inf[j] = sv[j] * mv[j];
    fb[j]  = (__bf16)(rc * (xv[j] + inf[j]));
  }
  ((f32x4*)out_x)[i]   = xv;
  ((f32x4*)out_inf)[i] = inf;
  ((bf16x4*)fusedb)[i] = fb;
}

// logits = fused @ W_cls^T + b_cls.  391 n-tiles x 4 m-tiles = 1564 blocks.
__global__ __launch_bounds__(256) void k_gemm_cls(
    const __bf16* __restrict__ fusedb, const float* __restrict__ Wcls,
    const float* __restrict__ bcls, float* __restrict__ out)
{
  __shared__ __bf16 lA[3 * 4096];
  __shared__ __bf16 lB[3 * 4096];
  // Bijective XCD chunk swizzle (1564 = 8*195 + 4), m innermost: each XCD gets
  // ~49 whole W_cls panels; a panel's 4 m-tiles stream it through one L2.
  const int xcd = blockIdx.x & 7, idx = blockIdx.x >> 3;
  const int start = (xcd < 4) ? xcd * 196 : 784 + (xcd - 4) * 195;
  const int logical = start + idx;
  const int m0 = (logical & 3) * 128;
  const int n0 = (logical >> 2) * 128;

  f32x4 acc[4][4];
  gemm_core<128, true, false, true>(fusedb, NFEAT, Wcls, NFEAT, m0, n0, NFEAT,
                                    NCLS, lA, lB, acc);

  EPILOGUE_COORDS();
#pragma unroll
  for (int mi = 0; mi < 4; ++mi)
#pragma unroll
    for (int ni = 0; ni < 4; ++ni)
#pragma unroll
      for (int q = 0; q < 4; ++q) {
        const int row = m0 + (wr * 4 + mi) * 16 + lg * 4 + q;
        const int col = n0 + wc * 64 + ni * 16 + lr;
        if (col < NCLS)
          out[(size_t)row * NCLS + col] = acc[mi][ni][q] + bcls[col];
      }
}

// ---------------- launch ----------------
extern "C" void kernel_launch(void* const* d_in, const int* in_sizes, int n_in,
                              void* d_out, int out_size, void* d_ws, size_t ws_size,
                              hipStream_t stream)
{
  (void)in_sizes; (void)n_in; (void)out_size; (void)ws_size;

  const float* x     = (const float*)d_in[0];
  const float* cent  = (const float*)d_in[1];
  const float* Whall = (const float*)d_in[2];
  const float* bhall = (const float*)d_in[3];
  const float* Wsel  = (const float*)d_in[4];
  const float* bsel  = (const float*)d_in[5];
  const float* Wcls  = (const float*)d_in[6];
  const float* bcls  = (const float*)d_in[7];
  float* out = (float*)d_out;

  float* out_logits = out;
  float* out_x      = out + (size_t)NBATCH * NCLS;
  float* out_inf    = out_x + (size_t)NBATCH * NFEAT;

  // Scratch placement: everything dead before k_gemm_cls lives INSIDE the
  // logits region of d_out (102 MB, only written by the final kernel; harness
  // re-poisons it each call so no state carried). Only fusedb (read by
  // k_gemm_cls while it writes logits) + tiny c2/reach use d_ws (~2.03 MiB,
  // well under the proven-available size).
  char* sc = (char*)d_out;
  float*  S     = (float*) (sc);                 // 2 MiB  [512 x 1024 f32]
  float*  H     = (float*) (sc + (2u << 20));    // 2 MiB
  float*  selt  = (float*) (sc + (4u << 20));    // 4 MiB  [512 x 2048 f32]
  float*  memf  = (float*) (sc + (8u << 20));    // 4 MiB
  __bf16* P     = (__bf16*)(sc + (12u << 20));   // 1 MiB  [512 x 1024 bf16]
  __bf16* centT = (__bf16*)(sc + (13u << 20));   // 4 MiB  [2048 x 1024 bf16]
                                                 // end 17 MiB << 102.5 MB

  char* ws = (char*)d_ws;
  float*  c2     = (float*) (ws);                // 4 KiB (16K slot)
  float*  reach  = (float*) (ws + (16u << 10));  // 2 KiB (16K slot)
  __bf16* fusedb = (__bf16*)(ws + (32u << 10));  // 2 MiB

  k_rownorm<<<NCENT, 256, 0, stream>>>(cent, c2);
  k_tcent<<<dim3(NCENTP / 64, NFEAT / 64), 256, 0, stream>>>(cent, centT);
  k_gemm_big<<<256, 256, 0, stream>>>(x, cent, Whall, bhall, Wsel, bsel, c2,
                                      S, H, selt);
  k_rowred<<<NBATCH, 256, 0, stream>>>(x, S, H, P, reach);
  k_gemm_mem<<<128, 256, 0, stream>>>(P, centT, memf);
  k_fuse<<<(NBATCH * NFEAT) / 1024, 256, 0, stream>>>(x, selt, memf, reach,
                                                      out_x, out_inf, fusedb);
  k_gemm_cls<<<1564, 256, 0, stream>>>(fusedb, Wcls, bcls, out_logits);
}